// Round 7
// baseline (224.758 us; speedup 1.0000x reference)
//
#include <hip/hip_runtime.h>
#include <hip/hip_bf16.h>
#include <math.h>

// R7 = R6 source + TIMING PROBE #2: attn_apply x5 and proj x5 (both
// idempotent). Delta vs R6 (118.0us) = 4*(t_attn + t_proj) + ~8 gaps.
// Session measured ledger: fill~45 (harness), qkv=19.7 (R5 probe),
// kvstat~3-4 (R6 rewrite neutral), prep~5 (physics). attn/proj/gaps unmeasured.

#define TOK 4096
#define CDIM 512
#define NHEADS 8
#define DH 64
#define NBH 16
#define NSEQ 2048
#define NSLICE 16
#define SQRT_C 22.62741699796952f
#define ATTN_SCALE 0.125f

typedef unsigned short ushort_t;
typedef __attribute__((ext_vector_type(8))) short short8;
typedef __attribute__((ext_vector_type(4))) short short4v;
typedef __attribute__((ext_vector_type(16))) float f32x16;
typedef __attribute__((ext_vector_type(4))) float f32x4;

__device__ inline ushort_t f2b(float f) {
  __hip_bfloat16 h = __float2bfloat16(f);
  return *(ushort_t*)&h;
}
__device__ inline float b2f(ushort_t u) {
  unsigned int x = ((unsigned int)u) << 16;
  float f;
  __builtin_memcpy(&f, &x, 4);
  return f;
}
__device__ inline f32x16 fzero16() {
  f32x16 v;
#pragma unroll
  for (int i = 0; i < 16; ++i) v[i] = 0.0f;
  return v;
}
__device__ inline void gload16(const ushort_t* g, ushort_t* l) {
  __builtin_amdgcn_global_load_lds(
      (const __attribute__((address_space(1))) unsigned int*)g,
      (__attribute__((address_space(3))) unsigned int*)l, 16, 0, 0);
}

// ---------------------------------------------------------------------------
// prep: fused W_qkv/W_proj row-normalize + x bf16 copy + x inv-norm.
// ---------------------------------------------------------------------------
__global__ __launch_bounds__(256) void prep_kernel(
    const float* __restrict__ W_qkv, const float* __restrict__ W_proj,
    const float* __restrict__ x,
    ushort_t* __restrict__ Wqn, ushort_t* __restrict__ Wpn,
    ushort_t* __restrict__ xb, float* __restrict__ xs) {
  const int row_g = blockIdx.x * 4 + (threadIdx.x >> 6);   // 0..8191
  const int t = threadIdx.x & 63;
  const float* src;
  ushort_t* dst;
  int row;
  bool isx = false;
  if (row_g < 3072)      { src = W_qkv;  dst = Wqn; row = row_g; }
  else if (row_g < 4096) { src = W_proj; dst = Wpn; row = row_g - 3072; }
  else                   { src = x;      dst = xb;  row = row_g - 4096; isx = true; }

  const float4* p = (const float4*)(src + (size_t)row * CDIM);
  float4 a = p[t];
  float4 b = p[t + 64];
  float s = a.x * a.x + a.y * a.y + a.z * a.z + a.w * a.w
          + b.x * b.x + b.y * b.y + b.z * b.z + b.w * b.w;
#pragma unroll
  for (int off = 32; off > 0; off >>= 1) s += __shfl_down(s, off);
  s = __shfl(s, 0);
  float inv;
  if (isx) {
    if (t == 0) xs[row] = 1.0f / (sqrtf(s) * SQRT_C);
    inv = 1.0f;
  } else {
    inv = 1.0f / sqrtf(s);
  }
  short4v ya, yb;
  ya[0] = (short)f2b(a.x * inv); ya[1] = (short)f2b(a.y * inv);
  ya[2] = (short)f2b(a.z * inv); ya[3] = (short)f2b(a.w * inv);
  yb[0] = (short)f2b(b.x * inv); yb[1] = (short)f2b(b.y * inv);
  yb[2] = (short)f2b(b.z * inv); yb[3] = (short)f2b(b.w * inv);
  *(short4v*)&dst[(size_t)row * CDIM + t * 4] = ya;
  *(short4v*)&dst[(size_t)row * CDIM + 256 + t * 4] = yb;
}

// ---------------------------------------------------------------------------
// bcos GEMM, bf16 MFMA 16x16x32. 128m x 64ch tile, BK=64. R1 dbuf structure.
// MODE 0: Qb [bh][n][64] (x0.125); Kt/Vt TILED [bh][slice16][dh64][tok128].
// MODE 1: fp32 out; osum_p[8][4096] summed into pool post-loop.
// ---------------------------------------------------------------------------
template <int MODE>
__global__ __launch_bounds__(256) void gemm_mfma_kernel(
    const ushort_t* __restrict__ Ab,
    const ushort_t* __restrict__ Wn,
    const float* __restrict__ ascale,
    const float* __restrict__ osum_p,
    float* __restrict__ out,
    ushort_t* __restrict__ Qb, ushort_t* __restrict__ Ktb,
    ushort_t* __restrict__ Vtb,
    int P) {
  __shared__ __align__(16) ushort_t pool[32768];   // 64 KB: 2 buffers x 16384
  const int t = threadIdx.x;
  const int lane = t & 63;
  const int w = t >> 6;
  const int mq = w & 1, wq = w >> 1;
  const int l15 = lane & 15, l4 = lane >> 4;
  const int n0 = blockIdx.x * 64;
  const int mb = blockIdx.y * 128;

  const int srow = lane >> 2;
  const int sch = (lane & 3) * 8;
  const ushort_t* ag[2];
  const ushort_t* wg[2];
  int alo[2], wlo[2];
#pragma unroll
  for (int i = 0; i < 2; ++i) {
    int r = w * 32 + i * 16;
    ag[i] = Ab + (size_t)(mb + r + srow) * CDIM + sch;
    alo[i] = r * 32;
    int g = r >> 4;
    int grow = n0 + (g >> 1) * 16 + srow + (g & 1) * P;
    wg[i] = Wn + (size_t)grow * CDIM + sch;
    wlo[i] = 8192 + r * 32;
  }

  f32x4 acc[4][4];
#pragma unroll
  for (int i = 0; i < 4; ++i)
#pragma unroll
    for (int j = 0; j < 4; ++j) acc[i][j] = (f32x4){0.f, 0.f, 0.f, 0.f};

  auto stage = [&](int nb) {
    ushort_t* base = pool + nb * 16384;
#pragma unroll
    for (int h = 0; h < 2; ++h)
#pragma unroll
      for (int i = 0; i < 2; ++i) {
        gload16(ag[i] + h * 32, base + alo[i] + h * 4096);
        gload16(wg[i] + h * 32, base + wlo[i] + h * 4096);
      }
#pragma unroll
    for (int i = 0; i < 2; ++i) { ag[i] += 64; wg[i] += 64; }
  };

  stage(0);                                  // prologue: buffer 0, K-step 0
  for (int it = 0; it < 8; ++it) {
    const int cur = it & 1;
    if (it < 7) {
      stage(cur ^ 1);                        // issue next K-step's 8 loads
      asm volatile("s_waitcnt vmcnt(8)" ::: "memory");  // 8 oldest (cur buf) done
    } else {
      asm volatile("s_waitcnt vmcnt(0)" ::: "memory");
    }
    __builtin_amdgcn_s_barrier();            // cur buffer staged by ALL waves
    __builtin_amdgcn_sched_barrier(0);
    const ushort_t* rb = pool + cur * 16384;
#pragma unroll
    for (int h = 0; h < 2; ++h) {
      short8 af[4], wf[4];
#pragma unroll
      for (int i = 0; i < 4; ++i)
        af[i] = *(const short8*)(rb + h * 4096 + (mq * 64 + i * 16 + l15) * 32 + l4 * 8);
#pragma unroll
      for (int j = 0; j < 4; ++j)
        wf[j] = *(const short8*)(rb + 8192 + h * 4096 + (wq * 64 + j * 16 + l15) * 32 + l4 * 8);
#pragma unroll
      for (int i = 0; i < 4; ++i)
#pragma unroll
        for (int j = 0; j < 4; ++j)
          acc[i][j] = __builtin_amdgcn_mfma_f32_16x16x32_bf16(af[i], wf[j], acc[i][j], 0, 0, 0);
    }
    asm volatile("s_waitcnt lgkmcnt(0)" ::: "memory");  // my ds_reads retired
    __builtin_amdgcn_sched_barrier(0);
    __builtin_amdgcn_s_barrier();            // all reads done; buf re-stageable
    __builtin_amdgcn_sched_barrier(0);
  }

  if (MODE == 0) {
    const int which = n0 >> 9;
    const int h = (n0 & 511) >> 6;
    const int b = mb >> 11;
    const int bh = b * NHEADS + h;
    const int nsb = mb & 2047;
    __syncthreads();                     // staging pool now free for transpose
    if (which == 0) {
      // Q: LDS [n 128][dh 64] pad 72
#pragma unroll
      for (int i = 0; i < 4; ++i) {
        const int ml = mq * 64 + i * 16 + l4 * 4;
        const float4 asc = *(const float4*)&ascale[mb + ml];
        const float ascv[4] = {asc.x, asc.y, asc.z, asc.w};
#pragma unroll
        for (int jt = 0; jt < 2; ++jt) {
          const int dh = (wq * 2 + jt) * 16 + l15;
          f32x4 a0 = acc[i][2 * jt], a1 = acc[i][2 * jt + 1];
#pragma unroll
          for (int r = 0; r < 4; ++r) {
            float v = fmaxf(a0[r], a1[r]);
            pool[(ml + r) * 72 + dh] = f2b(v * fabsf(v) * ascv[r] * ATTN_SCALE);
          }
        }
      }
      __syncthreads();
      ushort_t* gq = Qb + ((size_t)bh * NSEQ + nsb) * DH;
#pragma unroll
      for (int p = 0; p < 4; ++p) {
        int idx = p * 256 + t;
        int row = idx >> 3, c8 = idx & 7;
        *(short8*)(gq + row * DH + c8 * 8) = *(const short8*)(pool + row * 72 + c8 * 8);
      }
    } else {
      // K/V: LDS [dh 64][n 128] pad 136; store as contiguous 16KB tile
#pragma unroll
      for (int i = 0; i < 4; ++i) {
        const int ml = mq * 64 + i * 16 + l4 * 4;
        const float4 asc = *(const float4*)&ascale[mb + ml];
        const float ascv[4] = {asc.x, asc.y, asc.z, asc.w};
#pragma unroll
        for (int jt = 0; jt < 2; ++jt) {
          const int dh = (wq * 2 + jt) * 16 + l15;
          f32x4 a0 = acc[i][2 * jt], a1 = acc[i][2 * jt + 1];
          short4v pv;
#pragma unroll
          for (int r = 0; r < 4; ++r) {
            float v = fmaxf(a0[r], a1[r]);
            pv[r] = (short)f2b(v * fabsf(v) * ascv[r]);
          }
          *(short4v*)(pool + dh * 136 + ml) = pv;
        }
      }
      __syncthreads();
      // tiled: [bh][slice][64][128], slice = nsb>>7, tile = 8192 ushorts
      ushort_t* gk = ((which == 1) ? Ktb : Vtb) +
                     ((size_t)bh * 16 + (nsb >> 7)) * 8192;
#pragma unroll
      for (int p = 0; p < 4; ++p) {
        int idx = p * 256 + t;
        int dh_r = idx >> 4, ch = idx & 15;
        *(short8*)(gk + dh_r * 128 + ch * 8) =
            *(const short8*)(pool + dh_r * 136 + ch * 8);
      }
    }
  } else {
    // osum reduction in the now-free pool
    float* oslf = (float*)pool;
    __syncthreads();
    if (t < 128) {
      float s = 0.f;
#pragma unroll
      for (int hh = 0; hh < 8; ++hh) s += osum_p[hh * TOK + mb + t];
      oslf[t] = s;
    }
    __syncthreads();
#pragma unroll
    for (int i = 0; i < 4; ++i) {
      const int ml = mq * 64 + i * 16 + l4 * 4;
      const int m = mb + ml;
      float ascv[4];
#pragma unroll
      for (int r = 0; r < 4; ++r) ascv[r] = 1.0f / (sqrtf(oslf[ml + r]) * SQRT_C);
#pragma unroll
      for (int jt = 0; jt < 2; ++jt) {
        const int c = n0 + (wq * 2 + jt) * 16 + l15;
        f32x4 a0 = acc[i][2 * jt], a1 = acc[i][2 * jt + 1];
#pragma unroll
        for (int r = 0; r < 4; ++r) {
          float v = fmaxf(a0[r], a1[r]);
          out[(size_t)(m + r) * CDIM + c] = v * fabsf(v) * ascv[r];
        }
      }
    }
  }
}

// ---------------------------------------------------------------------------
// kvstat R6: grid (16,16) = 256 blocks; contiguous 16KB tile reads; output-
// split waves; no cross-wave reduce. Agp layout unchanged.
// ---------------------------------------------------------------------------
__global__ __launch_bounds__(256) void kvstat_kernel(
    const ushort_t* __restrict__ Ktb,
    const ushort_t* __restrict__ Vtb,
    float* __restrict__ Agp) {
  __shared__ __align__(16) ushort_t Kl[64 * 136];
  __shared__ __align__(16) ushort_t Vl[64 * 136];
  const int t = threadIdx.x;
  const int lane = t & 63;
  const int w = t >> 6;
  const int l15 = lane & 15, l4 = lane >> 4;
  const int slice = blockIdx.x;
  const int bh = blockIdx.y;

  const ushort_t* Kg = Ktb + ((size_t)bh * 16 + slice) * 8192;
  const ushort_t* Vg = Vtb + ((size_t)bh * 16 + slice) * 8192;
  short8 kr[4], vr[4];
#pragma unroll
  for (int g = 0; g < 4; ++g) {
    int idx = g * 256 + t;               // 0..1023 granules of 16B
    int row = idx >> 4, seg = idx & 15;
    kr[g] = *(const short8*)(Kg + row * 128 + seg * 8);
    vr[g] = *(const short8*)(Vg + row * 128 + seg * 8);
  }
#pragma unroll
  for (int g = 0; g < 4; ++g) {
    int idx = g * 256 + t;
    int row = idx >> 4, seg = idx & 15;
    *(short8*)(Kl + row * 136 + seg * 8) = kr[g];
    *(short8*)(Vl + row * 136 + seg * 8) = vr[g];
  }
  __syncthreads();

  f32x4 acc[4];
#pragma unroll
  for (int nt = 0; nt < 4; ++nt) acc[nt] = (f32x4){0.f, 0.f, 0.f, 0.f};
#pragma unroll
  for (int ks = 0; ks < 4; ++ks) {
    short8 af = *(const short8*)(Vl + (w * 16 + l15) * 136 + ks * 32 + l4 * 8);
#pragma unroll
    for (int nt = 0; nt < 4; ++nt) {
      short8 bf = *(const short8*)(Kl + (nt * 16 + l15) * 136 + ks * 32 + l4 * 8);
      acc[nt] = __builtin_amdgcn_mfma_f32_16x16x32_bf16(af, bf, acc[nt], 0, 0, 0);
    }
  }

  float* ag = Agp + ((size_t)slice * NBH + bh) * (66 * 64);
#pragma unroll
  for (int nt = 0; nt < 4; ++nt)
#pragma unroll
    for (int r = 0; r < 4; ++r)
      ag[(w * 16 + l4 * 4 + r) * 64 + nt * 16 + l15] = acc[nt][r];

  if (t < 128) {
    const ushort_t* src = (t < 64) ? Kl : Vl;
    const int row = t & 63;
    float s = 0.f;
#pragma unroll
    for (int sg = 0; sg < 16; ++sg) {
      short8 v = *(const short8*)(src + row * 136 + sg * 8);
#pragma unroll
      for (int q = 0; q < 8; ++q) s += b2f((ushort_t)v[q]);
    }
    ag[(t < 64 ? 64 * 64 : 65 * 64) + row] = s;
  }
}

// ---------------------------------------------------------------------------
// attn_apply: attn = (vsum + q~.M)/(2048 + q~.ksum); sums 16 partial slices.
// ---------------------------------------------------------------------------
__global__ __launch_bounds__(256) void attn_apply_kernel(
    const ushort_t* __restrict__ Qb,
    const float* __restrict__ Agp,
    ushort_t* __restrict__ attnb,
    float* __restrict__ osum_p) {      // [8][4096]
  __shared__ ushort_t Bs[96 * 72];
  __shared__ float vs_lds[64];
  const int t = threadIdx.x;
  const int lane = t & 63;
  const int w = t >> 6;
  const int l31 = lane & 31;
  const int H = lane >> 5;
  const int bh = blockIdx.y;
  const int tok0 = blockIdx.x * 128 + w * 32;

  const float* agp = Agp + (size_t)bh * (66 * 64);
  const size_t sstr = (size_t)NBH * 66 * 64;
  for (int e = t; e < 64 * 64; e += 256) {
    float s = 0.f;
#pragma unroll
    for (int sl = 0; sl < NSLICE; ++sl) s += agp[sl * sstr + e];
    Bs[(e >> 6) * 72 + (e & 63)] = f2b(s);
  }
  for (int e = t; e < 32 * 64; e += 256) {
    int j = e >> 6, i = e & 63;
    ushort_t v = 0;
    if (j == 0) {
      float s = 0.f;
#pragma unroll
      for (int sl = 0; sl < NSLICE; ++sl) s += agp[sl * sstr + 64 * 64 + i];
      v = f2b(s);
    }
    Bs[(64 + j) * 72 + i] = v;
  }
  if (t < 64) {
    float s = 0.f;
#pragma unroll
    for (int sl = 0; sl < NSLICE; ++sl) s += agp[sl * sstr + 65 * 64 + t];
    vs_lds[t] = s;
  }
  __syncthreads();

  short8 qf[4];
  {
    const ushort_t* qp = Qb + ((size_t)bh * NSEQ + tok0 + l31) * DH + H * 8;
#pragma unroll
    for (int c = 0; c < 4; ++c) qf[c] = *(const short8*)(qp + c * 16);
  }

  f32x16 oacc[3];
#pragma unroll
  for (int nt = 0; nt < 3; ++nt) oacc[nt] = fzero16();
#pragma unroll
  for (int c = 0; c < 4; ++c) {
#pragma unroll
    for (int nt = 0; nt < 3; ++nt) {
      short8 bfr = *(const short8*)(Bs + (nt * 32 + l31) * 72 + c * 16 + H * 8);
      oacc[nt] = __builtin_amdgcn_mfma_f32_32x32x16_bf16(qf[c], bfr, oacc[nt], 0, 0, 0);
    }
  }

  const int b = bh >> 3, h = bh & 7;
#pragma unroll
  for (int r = 0; r < 16; ++r) {
    int rloc = (r & 3) + 8 * (r >> 2) + 4 * H;
    float den = 2048.0f + __shfl(oacc[2][r], H * 32);
    float inv = 1.0f / den;
    float v0 = (vs_lds[l31] + oacc[0][r]) * inv;
    float v1 = (vs_lds[32 + l31] + oacc[1][r]) * inv;
    int n = tok0 + rloc;
    ushort_t* op = attnb + ((size_t)(b * NSEQ + n)) * CDIM + h * DH;
    op[l31] = f2b(v0);
    op[32 + l31] = f2b(v1);
    float ss = v0 * v0 + v1 * v1;
#pragma unroll
    for (int off = 16; off > 0; off >>= 1) ss += __shfl_down(ss, off, 32);
    if (l31 == 0) osum_p[h * TOK + b * NSEQ + n] = ss;
  }
}

extern "C" void kernel_launch(void* const* d_in, const int* in_sizes, int n_in,
                              void* d_out, int out_size, void* d_ws, size_t ws_size,
                              hipStream_t stream) {
  const float* x      = (const float*)d_in[0];
  const float* W_qkv  = (const float*)d_in[1];
  const float* W_proj = (const float*)d_in[2];
  float* out = (float*)d_out;

  char* wsb = (char*)d_ws;
  ushort_t* Wqn = (ushort_t*)(wsb + 0);          // 3072x512 bf16
  ushort_t* Wpn = (ushort_t*)(wsb + 3145728);    // 1024x512 bf16
  ushort_t* xb  = (ushort_t*)(wsb + 4194304);    // 4096x512 bf16; reused as attnb
  ushort_t* Qb  = (ushort_t*)(wsb + 8388608);    // [bh][n][64] bf16
  ushort_t* Ktb = (ushort_t*)(wsb + 12582912);   // [bh][slice][64][128] bf16 tiles
  ushort_t* Vtb = (ushort_t*)(wsb + 16777216);   // [bh][slice][64][128] bf16 tiles
  float* xs     = (float*)(wsb + 20971520);      // 4096
  float* osum_p = (float*)(wsb + 20987904);      // 8 x 4096
  float* Agp    = (float*)(wsb + 21118976);      // 16 x 16 x 66*64 (4.33 MB)

  prep_kernel<<<2048, 256, 0, stream>>>(W_qkv, W_proj, x, Wqn, Wpn, xb, xs);

  gemm_mfma_kernel<0><<<dim3(24, 32), 256, 0, stream>>>(
      xb, Wqn, xs, nullptr, nullptr, Qb, Ktb, Vtb, 1536);

  kvstat_kernel<<<dim3(16, NBH), 256, 0, stream>>>(Ktb, Vtb, Agp);

  // TIMING PROBE #2: attn_apply and proj are idempotent; x5 each.
  // Delta vs 118.0 = 4*(t_attn + t_proj) + ~8 launch gaps.
  for (int rep = 0; rep < 5; ++rep) {
    attn_apply_kernel<<<dim3(16, NBH), 256, 0, stream>>>(Qb, Agp, xb, osum_p);
  }
  for (int rep = 0; rep < 5; ++rep) {
    gemm_mfma_kernel<1><<<dim3(8, 32), 256, 0, stream>>>(
        xb, Wpn, nullptr, osum_p, out, nullptr, nullptr, nullptr, 512);
  }
}

// Round 8
// 113.905 us; speedup vs baseline: 1.9732x; 1.9732x over previous
//
#include <hip/hip_runtime.h>
#include <hip/hip_bf16.h>
#include <math.h>

// R8 = R6 base + Agr atomic reduction: kvstat atomicAdds into Agr[bh][4224]
// (zeroed by prep), attn prologue reads it once (was: 16-slice re-reduce per
// block, 69MB redundant L2 traffic). Measured ledger: fill~45 (harness),
// prep~5, qkv=19.7 (R5), kvstat~3.5, attn+proj~26 (R7), gaps~18.

#define TOK 4096
#define CDIM 512
#define NHEADS 8
#define DH 64
#define NBH 16
#define NSEQ 2048
#define SQRT_C 22.62741699796952f
#define ATTN_SCALE 0.125f

typedef unsigned short ushort_t;
typedef __attribute__((ext_vector_type(8))) short short8;
typedef __attribute__((ext_vector_type(4))) short short4v;
typedef __attribute__((ext_vector_type(16))) float f32x16;
typedef __attribute__((ext_vector_type(4))) float f32x4;

__device__ inline ushort_t f2b(float f) {
  __hip_bfloat16 h = __float2bfloat16(f);
  return *(ushort_t*)&h;
}
__device__ inline float b2f(ushort_t u) {
  unsigned int x = ((unsigned int)u) << 16;
  float f;
  __builtin_memcpy(&f, &x, 4);
  return f;
}
__device__ inline f32x16 fzero16() {
  f32x16 v;
#pragma unroll
  for (int i = 0; i < 16; ++i) v[i] = 0.0f;
  return v;
}
__device__ inline void gload16(const ushort_t* g, ushort_t* l) {
  __builtin_amdgcn_global_load_lds(
      (const __attribute__((address_space(1))) unsigned int*)g,
      (__attribute__((address_space(3))) unsigned int*)l, 16, 0, 0);
}

// ---------------------------------------------------------------------------
// prep: W row-normalize + x bf16 copy + x inv-norm + Agr zero-init.
// ---------------------------------------------------------------------------
__global__ __launch_bounds__(256) void prep_kernel(
    const float* __restrict__ W_qkv, const float* __restrict__ W_proj,
    const float* __restrict__ x,
    ushort_t* __restrict__ Wqn, ushort_t* __restrict__ Wpn,
    ushort_t* __restrict__ xb, float* __restrict__ xs,
    float* __restrict__ Agr) {
  // Agr zero-init: 16*4224 = 67584 floats = 66 blocks x 256 thr x float4
  if (blockIdx.x < 66) {
    float4 z = {0.f, 0.f, 0.f, 0.f};
    *(float4*)&Agr[(size_t)blockIdx.x * 1024 + threadIdx.x * 4] = z;
  }

  const int row_g = blockIdx.x * 4 + (threadIdx.x >> 6);   // 0..8191
  const int t = threadIdx.x & 63;
  const float* src;
  ushort_t* dst;
  int row;
  bool isx = false;
  if (row_g < 3072)      { src = W_qkv;  dst = Wqn; row = row_g; }
  else if (row_g < 4096) { src = W_proj; dst = Wpn; row = row_g - 3072; }
  else                   { src = x;      dst = xb;  row = row_g - 4096; isx = true; }

  const float4* p = (const float4*)(src + (size_t)row * CDIM);
  float4 a = p[t];
  float4 b = p[t + 64];
  float s = a.x * a.x + a.y * a.y + a.z * a.z + a.w * a.w
          + b.x * b.x + b.y * b.y + b.z * b.z + b.w * b.w;
#pragma unroll
  for (int off = 32; off > 0; off >>= 1) s += __shfl_down(s, off);
  s = __shfl(s, 0);
  float inv;
  if (isx) {
    if (t == 0) xs[row] = 1.0f / (sqrtf(s) * SQRT_C);
    inv = 1.0f;
  } else {
    inv = 1.0f / sqrtf(s);
  }
  short4v ya, yb;
  ya[0] = (short)f2b(a.x * inv); ya[1] = (short)f2b(a.y * inv);
  ya[2] = (short)f2b(a.z * inv); ya[3] = (short)f2b(a.w * inv);
  yb[0] = (short)f2b(b.x * inv); yb[1] = (short)f2b(b.y * inv);
  yb[2] = (short)f2b(b.z * inv); yb[3] = (short)f2b(b.w * inv);
  *(short4v*)&dst[(size_t)row * CDIM + t * 4] = ya;
  *(short4v*)&dst[(size_t)row * CDIM + 256 + t * 4] = yb;
}

// ---------------------------------------------------------------------------
// bcos GEMM, bf16 MFMA 16x16x32. 128m x 64ch tile, BK=64. R1 dbuf structure.
// MODE 0: Qb [bh][n][64] (x0.125); Kt/Vt TILED [bh][slice16][dh64][tok128].
// MODE 1: fp32 out; osum_p[8][4096] summed into pool post-loop.
// ---------------------------------------------------------------------------
template <int MODE>
__global__ __launch_bounds__(256) void gemm_mfma_kernel(
    const ushort_t* __restrict__ Ab,
    const ushort_t* __restrict__ Wn,
    const float* __restrict__ ascale,
    const float* __restrict__ osum_p,
    float* __restrict__ out,
    ushort_t* __restrict__ Qb, ushort_t* __restrict__ Ktb,
    ushort_t* __restrict__ Vtb,
    int P) {
  __shared__ __align__(16) ushort_t pool[32768];   // 64 KB: 2 buffers x 16384
  const int t = threadIdx.x;
  const int lane = t & 63;
  const int w = t >> 6;
  const int mq = w & 1, wq = w >> 1;
  const int l15 = lane & 15, l4 = lane >> 4;
  const int n0 = blockIdx.x * 64;
  const int mb = blockIdx.y * 128;

  const int srow = lane >> 2;
  const int sch = (lane & 3) * 8;
  const ushort_t* ag[2];
  const ushort_t* wg[2];
  int alo[2], wlo[2];
#pragma unroll
  for (int i = 0; i < 2; ++i) {
    int r = w * 32 + i * 16;
    ag[i] = Ab + (size_t)(mb + r + srow) * CDIM + sch;
    alo[i] = r * 32;
    int g = r >> 4;
    int grow = n0 + (g >> 1) * 16 + srow + (g & 1) * P;
    wg[i] = Wn + (size_t)grow * CDIM + sch;
    wlo[i] = 8192 + r * 32;
  }

  f32x4 acc[4][4];
#pragma unroll
  for (int i = 0; i < 4; ++i)
#pragma unroll
    for (int j = 0; j < 4; ++j) acc[i][j] = (f32x4){0.f, 0.f, 0.f, 0.f};

  auto stage = [&](int nb) {
    ushort_t* base = pool + nb * 16384;
#pragma unroll
    for (int h = 0; h < 2; ++h)
#pragma unroll
      for (int i = 0; i < 2; ++i) {
        gload16(ag[i] + h * 32, base + alo[i] + h * 4096);
        gload16(wg[i] + h * 32, base + wlo[i] + h * 4096);
      }
#pragma unroll
    for (int i = 0; i < 2; ++i) { ag[i] += 64; wg[i] += 64; }
  };

  stage(0);                                  // prologue: buffer 0, K-step 0
  for (int it = 0; it < 8; ++it) {
    const int cur = it & 1;
    if (it < 7) {
      stage(cur ^ 1);                        // issue next K-step's 8 loads
      asm volatile("s_waitcnt vmcnt(8)" ::: "memory");  // 8 oldest (cur buf) done
    } else {
      asm volatile("s_waitcnt vmcnt(0)" ::: "memory");
    }
    __builtin_amdgcn_s_barrier();            // cur buffer staged by ALL waves
    __builtin_amdgcn_sched_barrier(0);
    const ushort_t* rb = pool + cur * 16384;
#pragma unroll
    for (int h = 0; h < 2; ++h) {
      short8 af[4], wf[4];
#pragma unroll
      for (int i = 0; i < 4; ++i)
        af[i] = *(const short8*)(rb + h * 4096 + (mq * 64 + i * 16 + l15) * 32 + l4 * 8);
#pragma unroll
      for (int j = 0; j < 4; ++j)
        wf[j] = *(const short8*)(rb + 8192 + h * 4096 + (wq * 64 + j * 16 + l15) * 32 + l4 * 8);
#pragma unroll
      for (int i = 0; i < 4; ++i)
#pragma unroll
        for (int j = 0; j < 4; ++j)
          acc[i][j] = __builtin_amdgcn_mfma_f32_16x16x32_bf16(af[i], wf[j], acc[i][j], 0, 0, 0);
    }
    asm volatile("s_waitcnt lgkmcnt(0)" ::: "memory");  // my ds_reads retired
    __builtin_amdgcn_sched_barrier(0);
    __builtin_amdgcn_s_barrier();            // all reads done; buf re-stageable
    __builtin_amdgcn_sched_barrier(0);
  }

  if (MODE == 0) {
    const int which = n0 >> 9;
    const int h = (n0 & 511) >> 6;
    const int b = mb >> 11;
    const int bh = b * NHEADS + h;
    const int nsb = mb & 2047;
    __syncthreads();                     // staging pool now free for transpose
    if (which == 0) {
      // Q: LDS [n 128][dh 64] pad 72
#pragma unroll
      for (int i = 0; i < 4; ++i) {
        const int ml = mq * 64 + i * 16 + l4 * 4;
        const float4 asc = *(const float4*)&ascale[mb + ml];
        const float ascv[4] = {asc.x, asc.y, asc.z, asc.w};
#pragma unroll
        for (int jt = 0; jt < 2; ++jt) {
          const int dh = (wq * 2 + jt) * 16 + l15;
          f32x4 a0 = acc[i][2 * jt], a1 = acc[i][2 * jt + 1];
#pragma unroll
          for (int r = 0; r < 4; ++r) {
            float v = fmaxf(a0[r], a1[r]);
            pool[(ml + r) * 72 + dh] = f2b(v * fabsf(v) * ascv[r] * ATTN_SCALE);
          }
        }
      }
      __syncthreads();
      ushort_t* gq = Qb + ((size_t)bh * NSEQ + nsb) * DH;
#pragma unroll
      for (int p = 0; p < 4; ++p) {
        int idx = p * 256 + t;
        int row = idx >> 3, c8 = idx & 7;
        *(short8*)(gq + row * DH + c8 * 8) = *(const short8*)(pool + row * 72 + c8 * 8);
      }
    } else {
      // K/V: LDS [dh 64][n 128] pad 136; store as contiguous 16KB tile
#pragma unroll
      for (int i = 0; i < 4; ++i) {
        const int ml = mq * 64 + i * 16 + l4 * 4;
        const float4 asc = *(const float4*)&ascale[mb + ml];
        const float ascv[4] = {asc.x, asc.y, asc.z, asc.w};
#pragma unroll
        for (int jt = 0; jt < 2; ++jt) {
          const int dh = (wq * 2 + jt) * 16 + l15;
          f32x4 a0 = acc[i][2 * jt], a1 = acc[i][2 * jt + 1];
          short4v pv;
#pragma unroll
          for (int r = 0; r < 4; ++r) {
            float v = fmaxf(a0[r], a1[r]);
            pv[r] = (short)f2b(v * fabsf(v) * ascv[r]);
          }
          *(short4v*)(pool + dh * 136 + ml) = pv;
        }
      }
      __syncthreads();
      // tiled: [bh][slice][64][128], slice = nsb>>7, tile = 8192 ushorts
      ushort_t* gk = ((which == 1) ? Ktb : Vtb) +
                     ((size_t)bh * 16 + (nsb >> 7)) * 8192;
#pragma unroll
      for (int p = 0; p < 4; ++p) {
        int idx = p * 256 + t;
        int dh_r = idx >> 4, ch = idx & 15;
        *(short8*)(gk + dh_r * 128 + ch * 8) =
            *(const short8*)(pool + dh_r * 136 + ch * 8);
      }
    }
  } else {
    // osum reduction in the now-free pool
    float* oslf = (float*)pool;
    __syncthreads();
    if (t < 128) {
      float s = 0.f;
#pragma unroll
      for (int hh = 0; hh < 8; ++hh) s += osum_p[hh * TOK + mb + t];
      oslf[t] = s;
    }
    __syncthreads();
#pragma unroll
    for (int i = 0; i < 4; ++i) {
      const int ml = mq * 64 + i * 16 + l4 * 4;
      const int m = mb + ml;
      float ascv[4];
#pragma unroll
      for (int r = 0; r < 4; ++r) ascv[r] = 1.0f / (sqrtf(oslf[ml + r]) * SQRT_C);
#pragma unroll
      for (int jt = 0; jt < 2; ++jt) {
        const int c = n0 + (wq * 2 + jt) * 16 + l15;
        f32x4 a0 = acc[i][2 * jt], a1 = acc[i][2 * jt + 1];
#pragma unroll
        for (int r = 0; r < 4; ++r) {
          float v = fmaxf(a0[r], a1[r]);
          out[(size_t)(m + r) * CDIM + c] = v * fabsf(v) * ascv[r];
        }
      }
    }
  }
}

// ---------------------------------------------------------------------------
// kvstat R8: per-slice tiles as R6, but output via fp32 atomicAdd into
// Agr[bh][4224] (0..4095 M[d][dh], 4096..4159 ksum, 4160..4223 vsum).
// Agr zero-initialized by prep (stream-ordered). 16 contributors/element.
// ---------------------------------------------------------------------------
__global__ __launch_bounds__(256) void kvstat_kernel(
    const ushort_t* __restrict__ Ktb,
    const ushort_t* __restrict__ Vtb,
    float* __restrict__ Agr) {
  __shared__ __align__(16) ushort_t Kl[64 * 136];
  __shared__ __align__(16) ushort_t Vl[64 * 136];
  const int t = threadIdx.x;
  const int lane = t & 63;
  const int w = t >> 6;
  const int l15 = lane & 15, l4 = lane >> 4;
  const int slice = blockIdx.x;
  const int bh = blockIdx.y;

  const ushort_t* Kg = Ktb + ((size_t)bh * 16 + slice) * 8192;
  const ushort_t* Vg = Vtb + ((size_t)bh * 16 + slice) * 8192;
  short8 kr[4], vr[4];
#pragma unroll
  for (int g = 0; g < 4; ++g) {
    int idx = g * 256 + t;               // 0..1023 granules of 16B
    int row = idx >> 4, seg = idx & 15;
    kr[g] = *(const short8*)(Kg + row * 128 + seg * 8);
    vr[g] = *(const short8*)(Vg + row * 128 + seg * 8);
  }
#pragma unroll
  for (int g = 0; g < 4; ++g) {
    int idx = g * 256 + t;
    int row = idx >> 4, seg = idx & 15;
    *(short8*)(Kl + row * 136 + seg * 8) = kr[g];
    *(short8*)(Vl + row * 136 + seg * 8) = vr[g];
  }
  __syncthreads();

  f32x4 acc[4];
#pragma unroll
  for (int nt = 0; nt < 4; ++nt) acc[nt] = (f32x4){0.f, 0.f, 0.f, 0.f};
#pragma unroll
  for (int ks = 0; ks < 4; ++ks) {
    short8 af = *(const short8*)(Vl + (w * 16 + l15) * 136 + ks * 32 + l4 * 8);
#pragma unroll
    for (int nt = 0; nt < 4; ++nt) {
      short8 bf = *(const short8*)(Kl + (nt * 16 + l15) * 136 + ks * 32 + l4 * 8);
      acc[nt] = __builtin_amdgcn_mfma_f32_16x16x32_bf16(af, bf, acc[nt], 0, 0, 0);
    }
  }

  float* agr = Agr + (size_t)bh * 4224;
#pragma unroll
  for (int nt = 0; nt < 4; ++nt)
#pragma unroll
    for (int r = 0; r < 4; ++r)
      atomicAdd(&agr[(w * 16 + l4 * 4 + r) * 64 + nt * 16 + l15], acc[nt][r]);

  if (t < 128) {
    const ushort_t* src = (t < 64) ? Kl : Vl;
    const int row = t & 63;
    float s = 0.f;
#pragma unroll
    for (int sg = 0; sg < 16; ++sg) {
      short8 v = *(const short8*)(src + row * 136 + sg * 8);
#pragma unroll
      for (int q = 0; q < 8; ++q) s += b2f((ushort_t)v[q]);
    }
    atomicAdd(&agr[(t < 64 ? 4096 : 4160) + row], s);
  }
}

// ---------------------------------------------------------------------------
// attn_apply R8: prologue reads pre-reduced Agr[bh] once (16.9 KB, L2-hot;
// was 16-slice re-reduction per block). Rest identical to verified path.
// ---------------------------------------------------------------------------
__global__ __launch_bounds__(256) void attn_apply_kernel(
    const ushort_t* __restrict__ Qb,
    const float* __restrict__ Agr,
    ushort_t* __restrict__ attnb,
    float* __restrict__ osum_p) {      // [8][4096]
  __shared__ ushort_t Bs[96 * 72];
  __shared__ float vs_lds[64];
  const int t = threadIdx.x;
  const int lane = t & 63;
  const int w = t >> 6;
  const int l31 = lane & 31;
  const int H = lane >> 5;
  const int bh = blockIdx.y;
  const int tok0 = blockIdx.x * 128 + w * 32;

  const float* agr = Agr + (size_t)bh * 4224;
  for (int e = t; e < 64 * 64; e += 256)
    Bs[(e >> 6) * 72 + (e & 63)] = f2b(agr[e]);
  for (int e = t; e < 32 * 64; e += 256) {
    int j = e >> 6, i = e & 63;
    Bs[(64 + j) * 72 + i] = (j == 0) ? f2b(agr[4096 + i]) : (ushort_t)0;
  }
  if (t < 64) vs_lds[t] = agr[4160 + t];
  __syncthreads();

  short8 qf[4];
  {
    const ushort_t* qp = Qb + ((size_t)bh * NSEQ + tok0 + l31) * DH + H * 8;
#pragma unroll
    for (int c = 0; c < 4; ++c) qf[c] = *(const short8*)(qp + c * 16);
  }

  f32x16 oacc[3];
#pragma unroll
  for (int nt = 0; nt < 3; ++nt) oacc[nt] = fzero16();
#pragma unroll
  for (int c = 0; c < 4; ++c) {
#pragma unroll
    for (int nt = 0; nt < 3; ++nt) {
      short8 bfr = *(const short8*)(Bs + (nt * 32 + l31) * 72 + c * 16 + H * 8);
      oacc[nt] = __builtin_amdgcn_mfma_f32_32x32x16_bf16(qf[c], bfr, oacc[nt], 0, 0, 0);
    }
  }

  const int b = bh >> 3, h = bh & 7;
#pragma unroll
  for (int r = 0; r < 16; ++r) {
    int rloc = (r & 3) + 8 * (r >> 2) + 4 * H;
    float den = 2048.0f + __shfl(oacc[2][r], H * 32);
    float inv = 1.0f / den;
    float v0 = (vs_lds[l31] + oacc[0][r]) * inv;
    float v1 = (vs_lds[32 + l31] + oacc[1][r]) * inv;
    int n = tok0 + rloc;
    ushort_t* op = attnb + ((size_t)(b * NSEQ + n)) * CDIM + h * DH;
    op[l31] = f2b(v0);
    op[32 + l31] = f2b(v1);
    float ss = v0 * v0 + v1 * v1;
#pragma unroll
    for (int off = 16; off > 0; off >>= 1) ss += __shfl_down(ss, off, 32);
    if (l31 == 0) osum_p[h * TOK + b * NSEQ + n] = ss;
  }
}

extern "C" void kernel_launch(void* const* d_in, const int* in_sizes, int n_in,
                              void* d_out, int out_size, void* d_ws, size_t ws_size,
                              hipStream_t stream) {
  const float* x      = (const float*)d_in[0];
  const float* W_qkv  = (const float*)d_in[1];
  const float* W_proj = (const float*)d_in[2];
  float* out = (float*)d_out;

  char* wsb = (char*)d_ws;
  ushort_t* Wqn = (ushort_t*)(wsb + 0);          // 3072x512 bf16
  ushort_t* Wpn = (ushort_t*)(wsb + 3145728);    // 1024x512 bf16
  ushort_t* xb  = (ushort_t*)(wsb + 4194304);    // 4096x512 bf16; reused as attnb
  ushort_t* Qb  = (ushort_t*)(wsb + 8388608);    // [bh][n][64] bf16
  ushort_t* Ktb = (ushort_t*)(wsb + 12582912);   // [bh][slice][64][128] bf16 tiles
  ushort_t* Vtb = (ushort_t*)(wsb + 16777216);   // [bh][slice][64][128] bf16 tiles
  float* xs     = (float*)(wsb + 20971520);      // 4096
  float* osum_p = (float*)(wsb + 20987904);      // 8 x 4096
  float* Agr    = (float*)(wsb + 21118976);      // 16 x 4224 fp32 (264 KB)

  prep_kernel<<<2048, 256, 0, stream>>>(W_qkv, W_proj, x, Wqn, Wpn, xb, xs, Agr);

  gemm_mfma_kernel<0><<<dim3(24, 32), 256, 0, stream>>>(
      xb, Wqn, xs, nullptr, nullptr, Qb, Ktb, Vtb, 1536);

  kvstat_kernel<<<dim3(16, NBH), 256, 0, stream>>>(Ktb, Vtb, Agr);

  attn_apply_kernel<<<dim3(16, NBH), 256, 0, stream>>>(Qb, Agr, xb, osum_p);

  gemm_mfma_kernel<1><<<dim3(8, 32), 256, 0, stream>>>(
      xb, Wpn, nullptr, osum_p, out, nullptr, nullptr, nullptr, 512);
}

// Round 9
// 112.955 us; speedup vs baseline: 1.9898x; 1.0084x over previous
//
#include <hip/hip_runtime.h>
#include <hip/hip_bf16.h>
#include <math.h>

// R9 = R8 base + (a) proj re-tiled 64m x 64ch, 512 blocks = 2/CU (was 256 =
// 1/CU, zero wave overlap) + (b) qkv XCD-bijective swizzle (per-XCD working
// set 3.5MB fits 4MB L2; FETCH was ~3x ideal from cross-XCD duplication).
// Ledger: fill~44 (harness), prep~5, qkv=19.7, kvstat~4.5, attn+proj~22, gaps~18.

#define TOK 4096
#define CDIM 512
#define NHEADS 8
#define DH 64
#define NBH 16
#define NSEQ 2048
#define SQRT_C 22.62741699796952f
#define ATTN_SCALE 0.125f

typedef unsigned short ushort_t;
typedef __attribute__((ext_vector_type(8))) short short8;
typedef __attribute__((ext_vector_type(4))) short short4v;
typedef __attribute__((ext_vector_type(16))) float f32x16;
typedef __attribute__((ext_vector_type(4))) float f32x4;

__device__ inline ushort_t f2b(float f) {
  __hip_bfloat16 h = __float2bfloat16(f);
  return *(ushort_t*)&h;
}
__device__ inline float b2f(ushort_t u) {
  unsigned int x = ((unsigned int)u) << 16;
  float f;
  __builtin_memcpy(&f, &x, 4);
  return f;
}
__device__ inline f32x16 fzero16() {
  f32x16 v;
#pragma unroll
  for (int i = 0; i < 16; ++i) v[i] = 0.0f;
  return v;
}
__device__ inline void gload16(const ushort_t* g, ushort_t* l) {
  __builtin_amdgcn_global_load_lds(
      (const __attribute__((address_space(1))) unsigned int*)g,
      (__attribute__((address_space(3))) unsigned int*)l, 16, 0, 0);
}

// ---------------------------------------------------------------------------
// prep: W row-normalize + x bf16 copy + x inv-norm + Agr zero-init.
// ---------------------------------------------------------------------------
__global__ __launch_bounds__(256) void prep_kernel(
    const float* __restrict__ W_qkv, const float* __restrict__ W_proj,
    const float* __restrict__ x,
    ushort_t* __restrict__ Wqn, ushort_t* __restrict__ Wpn,
    ushort_t* __restrict__ xb, float* __restrict__ xs,
    float* __restrict__ Agr) {
  // Agr zero-init: 16*4224 = 67584 floats = 66 blocks x 256 thr x float4
  if (blockIdx.x < 66) {
    float4 z = {0.f, 0.f, 0.f, 0.f};
    *(float4*)&Agr[(size_t)blockIdx.x * 1024 + threadIdx.x * 4] = z;
  }

  const int row_g = blockIdx.x * 4 + (threadIdx.x >> 6);   // 0..8191
  const int t = threadIdx.x & 63;
  const float* src;
  ushort_t* dst;
  int row;
  bool isx = false;
  if (row_g < 3072)      { src = W_qkv;  dst = Wqn; row = row_g; }
  else if (row_g < 4096) { src = W_proj; dst = Wpn; row = row_g - 3072; }
  else                   { src = x;      dst = xb;  row = row_g - 4096; isx = true; }

  const float4* p = (const float4*)(src + (size_t)row * CDIM);
  float4 a = p[t];
  float4 b = p[t + 64];
  float s = a.x * a.x + a.y * a.y + a.z * a.z + a.w * a.w
          + b.x * b.x + b.y * b.y + b.z * b.z + b.w * b.w;
#pragma unroll
  for (int off = 32; off > 0; off >>= 1) s += __shfl_down(s, off);
  s = __shfl(s, 0);
  float inv;
  if (isx) {
    if (t == 0) xs[row] = 1.0f / (sqrtf(s) * SQRT_C);
    inv = 1.0f;
  } else {
    inv = 1.0f / sqrtf(s);
  }
  short4v ya, yb;
  ya[0] = (short)f2b(a.x * inv); ya[1] = (short)f2b(a.y * inv);
  ya[2] = (short)f2b(a.z * inv); ya[3] = (short)f2b(a.w * inv);
  yb[0] = (short)f2b(b.x * inv); yb[1] = (short)f2b(b.y * inv);
  yb[2] = (short)f2b(b.z * inv); yb[3] = (short)f2b(b.w * inv);
  *(short4v*)&dst[(size_t)row * CDIM + t * 4] = ya;
  *(short4v*)&dst[(size_t)row * CDIM + 256 + t * 4] = yb;
}

// ---------------------------------------------------------------------------
// qkv GEMM, bf16 MFMA 16x16x32. 128m x 64ch tile, BK=64, R1 dbuf structure.
// R9: XCD-bijective blockIdx swizzle (768 = 8 x 96): each XCD owns 4
// consecutive m-tiles x all 24 ch-tiles -> per-XCD set 3.5MB fits 4MB L2.
// Qb [bh][n][64] (x0.125); Kt/Vt TILED [bh][slice16][dh64][tok128].
// ---------------------------------------------------------------------------
__global__ __launch_bounds__(256) void qkv_kernel(
    const ushort_t* __restrict__ Ab,
    const ushort_t* __restrict__ Wn,
    const float* __restrict__ ascale,
    ushort_t* __restrict__ Qb, ushort_t* __restrict__ Ktb,
    ushort_t* __restrict__ Vtb,
    int P) {
  __shared__ __align__(16) ushort_t pool[32768];   // 64 KB: 2 buffers x 16384
  const int t = threadIdx.x;
  const int lane = t & 63;
  const int w = t >> 6;
  const int mq = w & 1, wq = w >> 1;
  const int l15 = lane & 15, l4 = lane >> 4;
  // XCD-bijective swizzle: bid -> swz; XCD k = bid%8 owns swz in [96k,96k+96)
  const int bid = blockIdx.x + 24 * blockIdx.y;    // 0..767
  const int swz = (bid & 7) * 96 + (bid >> 3);
  const int n0 = (swz % 24) * 64;
  const int mb = (swz / 24) * 128;

  const int srow = lane >> 2;
  const int sch = (lane & 3) * 8;
  const ushort_t* ag[2];
  const ushort_t* wg[2];
  int alo[2], wlo[2];
#pragma unroll
  for (int i = 0; i < 2; ++i) {
    int r = w * 32 + i * 16;
    ag[i] = Ab + (size_t)(mb + r + srow) * CDIM + sch;
    alo[i] = r * 32;
    int g = r >> 4;
    int grow = n0 + (g >> 1) * 16 + srow + (g & 1) * P;
    wg[i] = Wn + (size_t)grow * CDIM + sch;
    wlo[i] = 8192 + r * 32;
  }

  f32x4 acc[4][4];
#pragma unroll
  for (int i = 0; i < 4; ++i)
#pragma unroll
    for (int j = 0; j < 4; ++j) acc[i][j] = (f32x4){0.f, 0.f, 0.f, 0.f};

  auto stage = [&](int nb) {
    ushort_t* base = pool + nb * 16384;
#pragma unroll
    for (int h = 0; h < 2; ++h)
#pragma unroll
      for (int i = 0; i < 2; ++i) {
        gload16(ag[i] + h * 32, base + alo[i] + h * 4096);
        gload16(wg[i] + h * 32, base + wlo[i] + h * 4096);
      }
#pragma unroll
    for (int i = 0; i < 2; ++i) { ag[i] += 64; wg[i] += 64; }
  };

  stage(0);                                  // prologue: buffer 0, K-step 0
  for (int it = 0; it < 8; ++it) {
    const int cur = it & 1;
    if (it < 7) {
      stage(cur ^ 1);                        // issue next K-step's 8 loads
      asm volatile("s_waitcnt vmcnt(8)" ::: "memory");  // 8 oldest (cur buf) done
    } else {
      asm volatile("s_waitcnt vmcnt(0)" ::: "memory");
    }
    __builtin_amdgcn_s_barrier();            // cur buffer staged by ALL waves
    __builtin_amdgcn_sched_barrier(0);
    const ushort_t* rb = pool + cur * 16384;
#pragma unroll
    for (int h = 0; h < 2; ++h) {
      short8 af[4], wf[4];
#pragma unroll
      for (int i = 0; i < 4; ++i)
        af[i] = *(const short8*)(rb + h * 4096 + (mq * 64 + i * 16 + l15) * 32 + l4 * 8);
#pragma unroll
      for (int j = 0; j < 4; ++j)
        wf[j] = *(const short8*)(rb + 8192 + h * 4096 + (wq * 64 + j * 16 + l15) * 32 + l4 * 8);
#pragma unroll
      for (int i = 0; i < 4; ++i)
#pragma unroll
        for (int j = 0; j < 4; ++j)
          acc[i][j] = __builtin_amdgcn_mfma_f32_16x16x32_bf16(af[i], wf[j], acc[i][j], 0, 0, 0);
    }
    asm volatile("s_waitcnt lgkmcnt(0)" ::: "memory");  // my ds_reads retired
    __builtin_amdgcn_sched_barrier(0);
    __builtin_amdgcn_s_barrier();            // all reads done; buf re-stageable
    __builtin_amdgcn_sched_barrier(0);
  }

  const int which = n0 >> 9;
  const int h = (n0 & 511) >> 6;
  const int b = mb >> 11;
  const int bh = b * NHEADS + h;
  const int nsb = mb & 2047;
  __syncthreads();                     // staging pool now free for transpose
  if (which == 0) {
    // Q: LDS [n 128][dh 64] pad 72
#pragma unroll
    for (int i = 0; i < 4; ++i) {
      const int ml = mq * 64 + i * 16 + l4 * 4;
      const float4 asc = *(const float4*)&ascale[mb + ml];
      const float ascv[4] = {asc.x, asc.y, asc.z, asc.w};
#pragma unroll
      for (int jt = 0; jt < 2; ++jt) {
        const int dh = (wq * 2 + jt) * 16 + l15;
        f32x4 a0 = acc[i][2 * jt], a1 = acc[i][2 * jt + 1];
#pragma unroll
        for (int r = 0; r < 4; ++r) {
          float v = fmaxf(a0[r], a1[r]);
          pool[(ml + r) * 72 + dh] = f2b(v * fabsf(v) * ascv[r] * ATTN_SCALE);
        }
      }
    }
    __syncthreads();
    ushort_t* gq = Qb + ((size_t)bh * NSEQ + nsb) * DH;
#pragma unroll
    for (int p = 0; p < 4; ++p) {
      int idx = p * 256 + t;
      int row = idx >> 3, c8 = idx & 7;
      *(short8*)(gq + row * DH + c8 * 8) = *(const short8*)(pool + row * 72 + c8 * 8);
    }
  } else {
    // K/V: LDS [dh 64][n 128] pad 136; store as contiguous 16KB tile
#pragma unroll
    for (int i = 0; i < 4; ++i) {
      const int ml = mq * 64 + i * 16 + l4 * 4;
      const float4 asc = *(const float4*)&ascale[mb + ml];
      const float ascv[4] = {asc.x, asc.y, asc.z, asc.w};
#pragma unroll
      for (int jt = 0; jt < 2; ++jt) {
        const int dh = (wq * 2 + jt) * 16 + l15;
        f32x4 a0 = acc[i][2 * jt], a1 = acc[i][2 * jt + 1];
        short4v pv;
#pragma unroll
        for (int r = 0; r < 4; ++r) {
          float v = fmaxf(a0[r], a1[r]);
          pv[r] = (short)f2b(v * fabsf(v) * ascv[r]);
        }
        *(short4v*)(pool + dh * 136 + ml) = pv;
      }
    }
    __syncthreads();
    // tiled: [bh][slice][64][128], slice = nsb>>7, tile = 8192 ushorts
    ushort_t* gk = ((which == 1) ? Ktb : Vtb) +
                   ((size_t)bh * 16 + (nsb >> 7)) * 8192;
#pragma unroll
    for (int p = 0; p < 4; ++p) {
      int idx = p * 256 + t;
      int dh_r = idx >> 4, ch = idx & 15;
      *(short8*)(gk + dh_r * 128 + ch * 8) =
          *(const short8*)(pool + dh_r * 136 + ch * 8);
    }
  }
}

// ---------------------------------------------------------------------------
// kvstat: per-slice tiles, fp32 atomicAdd into Agr[bh][4224] (R8 structure).
// ---------------------------------------------------------------------------
__global__ __launch_bounds__(256) void kvstat_kernel(
    const ushort_t* __restrict__ Ktb,
    const ushort_t* __restrict__ Vtb,
    float* __restrict__ Agr) {
  __shared__ __align__(16) ushort_t Kl[64 * 136];
  __shared__ __align__(16) ushort_t Vl[64 * 136];
  const int t = threadIdx.x;
  const int lane = t & 63;
  const int w = t >> 6;
  const int l15 = lane & 15, l4 = lane >> 4;
  const int slice = blockIdx.x;
  const int bh = blockIdx.y;

  const ushort_t* Kg = Ktb + ((size_t)bh * 16 + slice) * 8192;
  const ushort_t* Vg = Vtb + ((size_t)bh * 16 + slice) * 8192;
  short8 kr[4], vr[4];
#pragma unroll
  for (int g = 0; g < 4; ++g) {
    int idx = g * 256 + t;               // 0..1023 granules of 16B
    int row = idx >> 4, seg = idx & 15;
    kr[g] = *(const short8*)(Kg + row * 128 + seg * 8);
    vr[g] = *(const short8*)(Vg + row * 128 + seg * 8);
  }
#pragma unroll
  for (int g = 0; g < 4; ++g) {
    int idx = g * 256 + t;
    int row = idx >> 4, seg = idx & 15;
    *(short8*)(Kl + row * 136 + seg * 8) = kr[g];
    *(short8*)(Vl + row * 136 + seg * 8) = vr[g];
  }
  __syncthreads();

  f32x4 acc[4];
#pragma unroll
  for (int nt = 0; nt < 4; ++nt) acc[nt] = (f32x4){0.f, 0.f, 0.f, 0.f};
#pragma unroll
  for (int ks = 0; ks < 4; ++ks) {
    short8 af = *(const short8*)(Vl + (w * 16 + l15) * 136 + ks * 32 + l4 * 8);
#pragma unroll
    for (int nt = 0; nt < 4; ++nt) {
      short8 bf = *(const short8*)(Kl + (nt * 16 + l15) * 136 + ks * 32 + l4 * 8);
      acc[nt] = __builtin_amdgcn_mfma_f32_16x16x32_bf16(af, bf, acc[nt], 0, 0, 0);
    }
  }

  float* agr = Agr + (size_t)bh * 4224;
#pragma unroll
  for (int nt = 0; nt < 4; ++nt)
#pragma unroll
    for (int r = 0; r < 4; ++r)
      atomicAdd(&agr[(w * 16 + l4 * 4 + r) * 64 + nt * 16 + l15], acc[nt][r]);

  if (t < 128) {
    const ushort_t* src = (t < 64) ? Kl : Vl;
    const int row = t & 63;
    float s = 0.f;
#pragma unroll
    for (int sg = 0; sg < 16; ++sg) {
      short8 v = *(const short8*)(src + row * 136 + sg * 8);
#pragma unroll
      for (int q = 0; q < 8; ++q) s += b2f((ushort_t)v[q]);
    }
    atomicAdd(&agr[(t < 64 ? 4096 : 4160) + row], s);
  }
}

// ---------------------------------------------------------------------------
// attn_apply: prologue reads pre-reduced Agr[bh] once (R8 structure).
// ---------------------------------------------------------------------------
__global__ __launch_bounds__(256) void attn_apply_kernel(
    const ushort_t* __restrict__ Qb,
    const float* __restrict__ Agr,
    ushort_t* __restrict__ attnb,
    float* __restrict__ osum_p) {      // [8][4096]
  __shared__ ushort_t Bs[96 * 72];
  __shared__ float vs_lds[64];
  const int t = threadIdx.x;
  const int lane = t & 63;
  const int w = t >> 6;
  const int l31 = lane & 31;
  const int H = lane >> 5;
  const int bh = blockIdx.y;
  const int tok0 = blockIdx.x * 128 + w * 32;

  const float* agr = Agr + (size_t)bh * 4224;
  for (int e = t; e < 64 * 64; e += 256)
    Bs[(e >> 6) * 72 + (e & 63)] = f2b(agr[e]);
  for (int e = t; e < 32 * 64; e += 256) {
    int j = e >> 6, i = e & 63;
    Bs[(64 + j) * 72 + i] = (j == 0) ? f2b(agr[4096 + i]) : (ushort_t)0;
  }
  if (t < 64) vs_lds[t] = agr[4160 + t];
  __syncthreads();

  short8 qf[4];
  {
    const ushort_t* qp = Qb + ((size_t)bh * NSEQ + tok0 + l31) * DH + H * 8;
#pragma unroll
    for (int c = 0; c < 4; ++c) qf[c] = *(const short8*)(qp + c * 16);
  }

  f32x16 oacc[3];
#pragma unroll
  for (int nt = 0; nt < 3; ++nt) oacc[nt] = fzero16();
#pragma unroll
  for (int c = 0; c < 4; ++c) {
#pragma unroll
    for (int nt = 0; nt < 3; ++nt) {
      short8 bfr = *(const short8*)(Bs + (nt * 32 + l31) * 72 + c * 16 + H * 8);
      oacc[nt] = __builtin_amdgcn_mfma_f32_32x32x16_bf16(qf[c], bfr, oacc[nt], 0, 0, 0);
    }
  }

  const int b = bh >> 3, h = bh & 7;
#pragma unroll
  for (int r = 0; r < 16; ++r) {
    int rloc = (r & 3) + 8 * (r >> 2) + 4 * H;
    float den = 2048.0f + __shfl(oacc[2][r], H * 32);
    float inv = 1.0f / den;
    float v0 = (vs_lds[l31] + oacc[0][r]) * inv;
    float v1 = (vs_lds[32 + l31] + oacc[1][r]) * inv;
    int n = tok0 + rloc;
    ushort_t* op = attnb + ((size_t)(b * NSEQ + n)) * CDIM + h * DH;
    op[l31] = f2b(v0);
    op[32 + l31] = f2b(v1);
    float ss = v0 * v0 + v1 * v1;
#pragma unroll
    for (int off = 16; off > 0; off >>= 1) ss += __shfl_down(ss, off, 32);
    if (l31 == 0) osum_p[h * TOK + b * NSEQ + n] = ss;
  }
}

// ---------------------------------------------------------------------------
// proj R9: 64m x 64ch tiles, grid (8,64) = 512 blocks = 2/CU (was 1/CU).
// Wave w owns all 64 m x 16 ch: accB[4]+accP[4]. 24 KB single-buffer LDS,
// BK=64 x 8 iters, 2 barriers/iter. Same K order -> bit-identical output.
// ---------------------------------------------------------------------------
__global__ __launch_bounds__(256) void proj_kernel(
    const ushort_t* __restrict__ Ab,
    const ushort_t* __restrict__ Wn,
    const float* __restrict__ osum_p,
    float* __restrict__ out) {
  __shared__ __align__(16) ushort_t pool[12288];  // A[2][64][32] | W[2][128][32]
  const int t = threadIdx.x;
  const int lane = t & 63;
  const int w = t >> 6;
  const int l15 = lane & 15, l4 = lane >> 4;
  const int n0 = blockIdx.x * 64;
  const int mb = blockIdx.y * 64;

  // staging: A 1 granule/thread/half, W 2 granules/thread/half (16B each)
  const ushort_t* ag;
  int alo;
  const ushort_t* wg[2];
  int wlo[2];
  {
    int arow = t >> 2, ks = t & 3;
    ag = Ab + (size_t)(mb + arow) * CDIM + ks * 8;
    alo = t * 8;
#pragma unroll
    for (int i = 0; i < 2; ++i) {
      int e = i * 256 + t;
      int r = e >> 2, bks = e & 3;
      int g = r >> 4;
      int grow = n0 + (g >> 1) * 16 + (r & 15) + (g & 1) * 512;
      wg[i] = Wn + (size_t)grow * CDIM + bks * 8;
      wlo[i] = e * 8;
    }
  }

  f32x4 accB[4], accP[4];
#pragma unroll
  for (int i = 0; i < 4; ++i) {
    accB[i] = (f32x4){0.f, 0.f, 0.f, 0.f};
    accP[i] = (f32x4){0.f, 0.f, 0.f, 0.f};
  }

  for (int it = 0; it < 8; ++it) {
    __syncthreads();                     // prior iteration's reads done
    gload16(ag,      pool + alo);                 // A h0
    gload16(ag + 32, pool + 2048 + alo);          // A h1
    gload16(wg[0],      pool + 4096 + wlo[0]);    // W h0
    gload16(wg[1],      pool + 4096 + wlo[1]);
    gload16(wg[0] + 32, pool + 8192 + wlo[0]);    // W h1
    gload16(wg[1] + 32, pool + 8192 + wlo[1]);
    ag += 64; wg[0] += 64; wg[1] += 64;
    __syncthreads();                     // staged (drains vmcnt+lgkm)
#pragma unroll
    for (int h = 0; h < 2; ++h) {
      const ushort_t* Al = pool + h * 2048;
      const ushort_t* Wl = pool + 4096 + h * 4096;
      short8 af[4];
#pragma unroll
      for (int i = 0; i < 4; ++i)
        af[i] = *(const short8*)(Al + (i * 16 + l15) * 32 + l4 * 8);
      short8 wfb = *(const short8*)(Wl + (w * 32 + l15) * 32 + l4 * 8);
      short8 wfp = *(const short8*)(Wl + (w * 32 + 16 + l15) * 32 + l4 * 8);
#pragma unroll
      for (int i = 0; i < 4; ++i) {
        accB[i] = __builtin_amdgcn_mfma_f32_16x16x32_bf16(af[i], wfb, accB[i], 0, 0, 0);
        accP[i] = __builtin_amdgcn_mfma_f32_16x16x32_bf16(af[i], wfp, accP[i], 0, 0, 0);
      }
    }
  }
  __syncthreads();                       // all reads done; pool reusable

  // osum reduce for this block's 64 m-rows
  float* oslf = (float*)pool;
  if (t < 64) {
    float s = 0.f;
#pragma unroll
    for (int hh = 0; hh < 8; ++hh) s += osum_p[hh * TOK + mb + t];
    oslf[t] = s;
  }
  __syncthreads();
  const int c = n0 + w * 16 + l15;
#pragma unroll
  for (int i = 0; i < 4; ++i) {
    const int ml = i * 16 + l4 * 4;
#pragma unroll
    for (int r = 0; r < 4; ++r) {
      float v = fmaxf(accB[i][r], accP[i][r]);
      float sc = 1.0f / (sqrtf(oslf[ml + r]) * SQRT_C);
      out[(size_t)(mb + ml + r) * CDIM + c] = v * fabsf(v) * sc;
    }
  }
}

extern "C" void kernel_launch(void* const* d_in, const int* in_sizes, int n_in,
                              void* d_out, int out_size, void* d_ws, size_t ws_size,
                              hipStream_t stream) {
  const float* x      = (const float*)d_in[0];
  const float* W_qkv  = (const float*)d_in[1];
  const float* W_proj = (const float*)d_in[2];
  float* out = (float*)d_out;

  char* wsb = (char*)d_ws;
  ushort_t* Wqn = (ushort_t*)(wsb + 0);          // 3072x512 bf16
  ushort_t* Wpn = (ushort_t*)(wsb + 3145728);    // 1024x512 bf16
  ushort_t* xb  = (ushort_t*)(wsb + 4194304);    // 4096x512 bf16; reused as attnb
  ushort_t* Qb  = (ushort_t*)(wsb + 8388608);    // [bh][n][64] bf16
  ushort_t* Ktb = (ushort_t*)(wsb + 12582912);   // [bh][slice][64][128] bf16 tiles
  ushort_t* Vtb = (ushort_t*)(wsb + 16777216);   // [bh][slice][64][128] bf16 tiles
  float* xs     = (float*)(wsb + 20971520);      // 4096
  float* osum_p = (float*)(wsb + 20987904);      // 8 x 4096
  float* Agr    = (float*)(wsb + 21118976);      // 16 x 4224 fp32 (264 KB)

  prep_kernel<<<2048, 256, 0, stream>>>(W_qkv, W_proj, x, Wqn, Wpn, xb, xs, Agr);

  qkv_kernel<<<dim3(24, 32), 256, 0, stream>>>(
      xb, Wqn, xs, Qb, Ktb, Vtb, 1536);

  kvstat_kernel<<<dim3(16, NBH), 256, 0, stream>>>(Ktb, Vtb, Agr);

  attn_apply_kernel<<<dim3(16, NBH), 256, 0, stream>>>(Qb, Agr, xb, osum_p);

  proj_kernel<<<dim3(8, 64), 256, 0, stream>>>(xb, Wpn, osum_p, out);
}